// Round 1
// baseline (525.162 us; speedup 1.0000x reference)
//
#include <hip/hip_runtime.h>
#include <hip/hip_bf16.h>

// SelfAttention: out = (softmax(mask(QK^T/32)) @ V) @ Wfc^T + bfc
// B=8, S=2048, D=1024. All GEMMs as bf16 MFMA (16x16x32), f32 accumulate.

#define DEVINL __device__ __forceinline__

typedef __bf16 bf16x8 __attribute__((ext_vector_type(8)));
typedef float f32x4 __attribute__((ext_vector_type(4)));

static constexpr int Bb = 8;
static constexpr int S = 2048;
static constexpr int D = 1024;

DEVINL unsigned short f32_to_bf16(float f) {
  unsigned u = __float_as_uint(f);
  u = (u + 0x7FFFu + ((u >> 16) & 1u)) >> 16;  // RNE, inputs finite
  return (unsigned short)u;
}

DEVINL float bf16_to_f32(unsigned short h) {
  return __uint_as_float(((unsigned)h) << 16);
}

DEVINL void gload16(const unsigned short* g, unsigned short* l) {
  // async global->LDS, 16B per lane; LDS dest is wave-uniform base + lane*16
  __builtin_amdgcn_global_load_lds((__attribute__((address_space(1))) void*)g,
                                   (__attribute__((address_space(3))) void*)l,
                                   16, 0, 0);
}

// ---------------- f32 -> bf16 conversion (vectorized, grid-stride) ----------
__global__ __launch_bounds__(256) void conv_f32_bf16(const float* __restrict__ in,
                                                     unsigned short* __restrict__ out,
                                                     int n8) {
  int i = blockIdx.x * 256 + threadIdx.x;
  int stride = gridDim.x * 256;
  for (; i < n8; i += stride) {
    const float4* p = (const float4*)in + (size_t)i * 2;
    float4 a = p[0], b = p[1];
    uint4 o;
    o.x = (unsigned)f32_to_bf16(a.x) | ((unsigned)f32_to_bf16(a.y) << 16);
    o.y = (unsigned)f32_to_bf16(a.z) | ((unsigned)f32_to_bf16(a.w) << 16);
    o.z = (unsigned)f32_to_bf16(b.x) | ((unsigned)f32_to_bf16(b.y) << 16);
    o.w = (unsigned)f32_to_bf16(b.z) | ((unsigned)f32_to_bf16(b.w) << 16);
    ((uint4*)out)[i] = o;
  }
}

// ---------------- bf16 GEMM: C[M,N] = A[M,K] * Bt[N,K]^T (both k-contig) ----
// 128x128 tile, BK=32, 4 waves (2x2), each wave 64x64 = 4x4 MFMA frags.
template <bool OUT_BF16, bool HAS_BIAS>
__global__ __launch_bounds__(256) void gemm_bt(const unsigned short* __restrict__ A,
                                               const unsigned short* __restrict__ Bt,
                                               const float* __restrict__ bias,
                                               void* __restrict__ Cv, int M, int N, int K,
                                               long long bsA, long long bsB, long long bsC,
                                               float scale) {
  const int tid = threadIdx.x;
  const int wave = tid >> 6;
  const int lane = tid & 63;
  const int wr = wave >> 1, wc = wave & 1;
  const int m0 = blockIdx.y * 128, n0 = blockIdx.x * 128;
  const int bz = blockIdx.z;
  A += (size_t)bz * bsA;
  Bt += (size_t)bz * bsB;

  __shared__ unsigned short lds[2][2][128 * 32];  // 32 KB: [buf][A/B][128 rows x 32 k]

  // staging map: linear row-major [128][32]; wave covers 16 rows per issue,
  // lane -> row srow, cols scol..scol+7 (16B)
  const int srow = wave * 16 + (lane >> 2);
  const int scol = (lane & 3) * 8;
  const unsigned short* gA = A + (size_t)(m0 + srow) * K + scol;
  const unsigned short* gB = Bt + (size_t)(n0 + srow) * K + scol;

  f32x4 acc[4][4];
#pragma unroll
  for (int i = 0; i < 4; i++)
#pragma unroll
    for (int j = 0; j < 4; j++) acc[i][j] = (f32x4){0.f, 0.f, 0.f, 0.f};

  const int nk = K >> 5;

  auto stage = [&](int buf, int kt) {
    const unsigned short* a0 = gA + (size_t)kt * 32;
    const unsigned short* b0 = gB + (size_t)kt * 32;
    unsigned short* la = &lds[buf][0][wave * 512];
    unsigned short* lb = &lds[buf][1][wave * 512];
    gload16(a0, la);
    gload16(a0 + (size_t)64 * K, la + 2048);
    gload16(b0, lb);
    gload16(b0 + (size_t)64 * K, lb + 2048);
  };

  stage(0, 0);
  asm volatile("s_waitcnt vmcnt(0)" ::: "memory");
  __syncthreads();

  const int fm = lane & 15;         // row/col within 16x16 frag
  const int fk = (lane >> 4) * 8;   // k offset (8 bf16)

  int cur = 0;
  for (int t = 0; t < nk; ++t) {
    if (t + 1 < nk) stage(cur ^ 1, t + 1);
    bf16x8 af[4], bfr[4];
#pragma unroll
    for (int i = 0; i < 4; i++)
      af[i] = *(const bf16x8*)&lds[cur][0][(wr * 64 + i * 16 + fm) * 32 + fk];
#pragma unroll
    for (int j = 0; j < 4; j++)
      bfr[j] = *(const bf16x8*)&lds[cur][1][(wc * 64 + j * 16 + fm) * 32 + fk];
#pragma unroll
    for (int i = 0; i < 4; i++)
#pragma unroll
      for (int j = 0; j < 4; j++)
        acc[i][j] = __builtin_amdgcn_mfma_f32_16x16x32_bf16(af[i], bfr[j], acc[i][j], 0, 0, 0);
    asm volatile("s_waitcnt vmcnt(0)" ::: "memory");
    __syncthreads();
    cur ^= 1;
  }

  // epilogue: D[row=(lane>>4)*4+r][col=lane&15] per frag (first operand -> rows)
  const int en = n0 + wc * 64 + fm;
  const int em = m0 + wr * 64 + ((lane >> 4) << 2);
#pragma unroll
  for (int j = 0; j < 4; j++) {
    const int n = en + j * 16;
    const float bv = HAS_BIAS ? bias[n] : 0.0f;
#pragma unroll
    for (int i = 0; i < 4; i++) {
      const int m = em + i * 16;
#pragma unroll
      for (int r = 0; r < 4; r++) {
        float v = acc[i][j][r] * scale + bv;
        size_t off = (size_t)bz * bsC + (size_t)(m + r) * N + n;
        if (OUT_BF16)
          ((unsigned short*)Cv)[off] = f32_to_bf16(v);
        else
          ((float*)Cv)[off] = v;
      }
    }
  }
}

// ---------------- row softmax over E [B*S][S] bf16, in-place --------------
// mask[b][q]==0 => whole row constant => softmax exactly uniform 1/S.
__global__ __launch_bounds__(256) void softmax_rows(unsigned short* __restrict__ E,
                                                    const int* __restrict__ mask) {
  const int row = blockIdx.x;  // 0..B*S-1
  const int b = row >> 11, q = row & 2047;
  unsigned short* R = E + (size_t)row * S;
  const int tid = threadIdx.x;
  const int wave = tid >> 6, lane = tid & 63;

  if (mask[b * S + q] == 0) {
    // uniform 1/2048 = bf16 0x3A00 exactly
    ((uint4*)R)[tid] = make_uint4(0x3A003A00u, 0x3A003A00u, 0x3A003A00u, 0x3A003A00u);
    return;
  }

  uint4 v = ((const uint4*)R)[tid];
  unsigned u[4] = {v.x, v.y, v.z, v.w};
  float f[8];
#pragma unroll
  for (int i = 0; i < 4; i++) {
    f[2 * i] = __uint_as_float(u[i] << 16);
    f[2 * i + 1] = __uint_as_float(u[i] & 0xFFFF0000u);
  }

  __shared__ float red[4];
  float m = f[0];
#pragma unroll
  for (int i = 1; i < 8; i++) m = fmaxf(m, f[i]);
#pragma unroll
  for (int off = 32; off >= 1; off >>= 1) m = fmaxf(m, __shfl_xor(m, off));
  if (lane == 0) red[wave] = m;
  __syncthreads();
  m = fmaxf(fmaxf(red[0], red[1]), fmaxf(red[2], red[3]));
  __syncthreads();

  float s = 0.f;
#pragma unroll
  for (int i = 0; i < 8; i++) {
    f[i] = __expf(f[i] - m);
    s += f[i];
  }
#pragma unroll
  for (int off = 32; off >= 1; off >>= 1) s += __shfl_xor(s, off);
  if (lane == 0) red[wave] = s;
  __syncthreads();
  s = red[0] + red[1] + red[2] + red[3];
  const float inv = 1.0f / s;

  uint4 o;
  unsigned* po = &o.x;
#pragma unroll
  for (int i = 0; i < 4; i++)
    po[i] = (unsigned)f32_to_bf16(f[2 * i] * inv) |
            ((unsigned)f32_to_bf16(f[2 * i + 1] * inv) << 16);
  ((uint4*)R)[tid] = o;
}

// ---------------- bf16 transpose: V[b][S][D] -> Vt[b][D][S], 64x64 tiles ---
__global__ __launch_bounds__(256) void transpose_bf16(const unsigned short* __restrict__ V,
                                                      unsigned short* __restrict__ Vt) {
  __shared__ unsigned short t[64][72];  // pad keeps 16B alignment (144B rows)
  const int d0 = blockIdx.x * 64, s0 = blockIdx.y * 64, b = blockIdx.z;
  const unsigned short* Vbp = V + (size_t)b * S * D;
  unsigned short* Vtb = Vt + (size_t)b * D * S;
  const int r = threadIdx.x >> 3;
  const int c8 = (threadIdx.x & 7) * 8;
#pragma unroll
  for (int i = 0; i < 2; i++) {
    int row = r + i * 32;
    uint4 v = *(const uint4*)(Vbp + (size_t)(s0 + row) * D + d0 + c8);
    *(uint4*)&t[row][c8] = v;
  }
  __syncthreads();
#pragma unroll
  for (int i = 0; i < 2; i++) {
    int rr = r + i * 32;
    unsigned short tmp[8];
#pragma unroll
    for (int j = 0; j < 8; j++) tmp[j] = t[c8 + j][rr];
    *(uint4*)(Vtb + (size_t)(d0 + rr) * S + s0 + c8) = *(const uint4*)tmp;
  }
}

// ---------------------------------------------------------------------------
extern "C" void kernel_launch(void* const* d_in, const int* in_sizes, int n_in,
                              void* d_out, int out_size, void* d_ws, size_t ws_size,
                              hipStream_t stream) {
  const float* q = (const float*)d_in[0];
  const float* k_ = (const float*)d_in[1];
  const float* v = (const float*)d_in[2];
  const int* msk = (const int*)d_in[3];
  const float* Wq = (const float*)d_in[4];
  const float* bq = (const float*)d_in[5];
  const float* Wk = (const float*)d_in[6];
  const float* bk = (const float*)d_in[7];
  const float* Wv = (const float*)d_in[8];
  const float* bv = (const float*)d_in[9];
  const float* Wfc = (const float*)d_in[10];
  const float* bfc = (const float*)d_in[11];

  char* ws = (char*)d_ws;
  const size_t MB = 1u << 20;
  unsigned short* WqB = (unsigned short*)(ws + 0 * MB);
  unsigned short* WkB = (unsigned short*)(ws + 2 * MB);
  unsigned short* WvB = (unsigned short*)(ws + 4 * MB);
  unsigned short* WfB = (unsigned short*)(ws + 6 * MB);
  unsigned short* Qb = (unsigned short*)(ws + 8 * MB);    // 32 MB
  unsigned short* Kb = (unsigned short*)(ws + 40 * MB);   // 32 MB
  unsigned short* Vt = (unsigned short*)(ws + 72 * MB);   // 32 MB
  unsigned short* Ab = (unsigned short*)(ws + 104 * MB);  // 32 MB (conv buf; later x)
  unsigned short* Vb = (unsigned short*)(ws + 136 * MB);  // 32 MB
  unsigned short* E = (unsigned short*)(ws + 136 * MB);   // 64 MB, aliases Vb (written after V consumed)

  const int NBS = Bb * S * D;  // 16.8M

  auto conv = [&](const float* in, unsigned short* out, int n) {
    int n8 = n / 8;
    int blocks = (n8 + 255) / 256;
    if (blocks > 2048) blocks = 2048;
    conv_f32_bf16<<<dim3(blocks), dim3(256), 0, stream>>>(in, out, n8);
  };

  conv(Wq, WqB, D * D);
  conv(Wk, WkB, D * D);
  conv(Wv, WvB, D * D);
  conv(Wfc, WfB, D * D);

  const float invscale = 1.0f / 32.0f;  // 1/sqrt(1024)

  // Q = query @ Wq^T + bq
  conv(q, Ab, NBS);
  gemm_bt<true, true><<<dim3(8, 128, 1), dim3(256), 0, stream>>>(
      Ab, WqB, bq, Qb, Bb * S, D, D, 0, 0, 0, 1.0f);
  // K = key_ @ Wk^T + bk
  conv(k_, Ab, NBS);
  gemm_bt<true, true><<<dim3(8, 128, 1), dim3(256), 0, stream>>>(
      Ab, WkB, bk, Kb, Bb * S, D, D, 0, 0, 0, 1.0f);
  // V = value @ Wv^T + bv
  conv(v, Ab, NBS);
  gemm_bt<true, true><<<dim3(8, 128, 1), dim3(256), 0, stream>>>(
      Ab, WvB, bv, Vb, Bb * S, D, D, 0, 0, 0, 1.0f);
  // Vt = V^T per batch
  transpose_bf16<<<dim3(16, 32, 8), dim3(256), 0, stream>>>(Vb, Vt);
  // E = Q @ K^T / 32   (per batch)
  gemm_bt<true, false><<<dim3(16, 16, 8), dim3(256), 0, stream>>>(
      Qb, Kb, nullptr, E, S, S, D, (long long)S * D, (long long)S * D,
      (long long)S * S, invscale);
  // P = softmax rows (mask rows -> uniform), in-place
  softmax_rows<<<dim3(Bb * S), dim3(256), 0, stream>>>(E, msk);
  // x = P @ V  (A=P k-contig, Bt=Vt[d][s] k-contig)
  gemm_bt<true, false><<<dim3(8, 16, 8), dim3(256), 0, stream>>>(
      E, Vt, nullptr, Ab, S, D, S, (long long)S * S, (long long)D * S,
      (long long)S * D, 1.0f);
  // out = x @ Wfc^T + bfc  (f32 out)
  gemm_bt<false, true><<<dim3(8, 128, 1), dim3(256), 0, stream>>>(
      Ab, WfB, bfc, d_out, Bb * S, D, D, 0, 0, 0, 1.0f);
}

// Round 2
// 427.051 us; speedup vs baseline: 1.2297x; 1.2297x over previous
//
#include <hip/hip_runtime.h>
#include <hip/hip_bf16.h>

// SelfAttention: out = (softmax(mask(QK^T/32)) @ V) @ Wfc^T + bfc
// B=8, S=2048, D=1024. All GEMMs bf16 MFMA 16x16x32, 256x256 tile, BK=64,
// 8 waves, 4-phase interleave, XOR-swizzled LDS, counted-late vmcnt.

#define DEVINL __device__ __forceinline__

typedef __bf16 bf16x8 __attribute__((ext_vector_type(8)));
typedef float f32x4 __attribute__((ext_vector_type(4)));

static constexpr int Bb = 8;
static constexpr int S = 2048;
static constexpr int D = 1024;

DEVINL unsigned short f32_to_bf16(float f) {
  unsigned u = __float_as_uint(f);
  u = (u + 0x7FFFu + ((u >> 16) & 1u)) >> 16;  // RNE, finite inputs
  return (unsigned short)u;
}

DEVINL void gload16(const unsigned short* g, char* l) {
  __builtin_amdgcn_global_load_lds((__attribute__((address_space(1))) void*)g,
                                   (__attribute__((address_space(3))) void*)l,
                                   16, 0, 0);
}

#define BAR() __builtin_amdgcn_s_barrier()
#define LGK0() asm volatile("s_waitcnt lgkmcnt(0)" ::: "memory")
#define VM0() asm volatile("s_waitcnt vmcnt(0)" ::: "memory")

// ---------------- f32 -> bf16 conversion -----------------------------------
__global__ __launch_bounds__(256) void conv_f32_bf16(const float* __restrict__ in,
                                                     unsigned short* __restrict__ out,
                                                     int n8) {
  int i = blockIdx.x * 256 + threadIdx.x;
  int stride = gridDim.x * 256;
  for (; i < n8; i += stride) {
    const float4* p = (const float4*)in + (size_t)i * 2;
    float4 a = p[0], b = p[1];
    uint4 o;
    o.x = (unsigned)f32_to_bf16(a.x) | ((unsigned)f32_to_bf16(a.y) << 16);
    o.y = (unsigned)f32_to_bf16(a.z) | ((unsigned)f32_to_bf16(a.w) << 16);
    o.z = (unsigned)f32_to_bf16(b.x) | ((unsigned)f32_to_bf16(b.y) << 16);
    o.w = (unsigned)f32_to_bf16(b.z) | ((unsigned)f32_to_bf16(b.w) << 16);
    ((uint4*)out)[i] = o;
  }
}

// ---------------- 256x256 GEMM: C[M,N] = A[M,K] * Bt[N,K]^T ----------------
// OUTMODE: 0 = f32, 1 = bf16, 2 = bf16 transposed per-batch (V -> Vt[b][n][s])
template <int OUTMODE, bool HAS_BIAS>
__global__ __launch_bounds__(512, 2) void gemm256(
    const unsigned short* __restrict__ A, const unsigned short* __restrict__ Bt,
    const float* __restrict__ bias, void* __restrict__ Cv,
    int M, int N, int K, long long bsA, long long bsB, long long bsC,
    float scale) {
  extern __shared__ char smem[];  // 2 bufs x (A 32KB + B 32KB) = 128KB
  const int tid = threadIdx.x;
  const int wave = tid >> 6, lane = tid & 63;
  const int wr = wave >> 2, wc = wave & 3;  // 2 x 4 wave grid

  // XCD-aware bijective swizzle (nwg % 8 == 0 for all our launches)
  const int gx = gridDim.x, gy = gridDim.y;
  const int nwg = gx * gy * (int)gridDim.z;
  const int wg = blockIdx.x + gx * (blockIdx.y + gy * blockIdx.z);
  const int swz = (wg & 7) * (nwg >> 3) + (wg >> 3);
  const int bx = swz % gx;
  const int rem = swz / gx;
  const int by = rem % gy;
  const int bz = rem / gy;

  const int m0 = by * 256, n0 = bx * 256;
  A += (size_t)bz * bsA;
  Bt += (size_t)bz * bsB;

  // ---- staging: per wave 4 chunks (8 rows x 128B each) of A and of B.
  // LDS physical granule (16B) within a row: g_phys = g_log ^ (row & 7).
  const int lr = lane >> 3;                 // row within chunk
  const int lg = (lane & 7) ^ lr;           // logical granule this lane fetches
  const int kgoff = lg * 8;                 // bf16 offset within the k-window

  auto stage = [&](int buf, int t) {
    const unsigned short* ga = A + (size_t)(m0 + wave * 32 + lr) * K + (size_t)t * 64 + kgoff;
    const unsigned short* gb = Bt + (size_t)(n0 + wave * 32 + lr) * K + (size_t)t * 64 + kgoff;
    char* la = smem + buf * 65536 + wave * 4096;
    char* lb = la + 32768;
#pragma unroll
    for (int i = 0; i < 4; i++) {
      gload16(ga + (size_t)i * 8 * K, la + i * 1024);
      gload16(gb + (size_t)i * 8 * K, lb + i * 1024);
    }
  };

  const int fr = lane & 15;  // row within 16x16 frag
  const int fg = lane >> 4;  // k-granule sub-index (0..3)
  auto readA = [&](int buf, int mi, int kc) -> bf16x8 {
    const int row = wr * 128 + mi * 16 + fr;
    const int g = (kc * 4 + fg) ^ (row & 7);
    return *(const bf16x8*)(smem + buf * 65536 + row * 128 + g * 16);
  };
  auto readB = [&](int buf, int nj, int kc) -> bf16x8 {
    const int row = wc * 64 + nj * 16 + fr;
    const int g = (kc * 4 + fg) ^ (row & 7);
    return *(const bf16x8*)(smem + buf * 65536 + 32768 + row * 128 + g * 16);
  };

  f32x4 acc[8][4];
#pragma unroll
  for (int i = 0; i < 8; i++)
#pragma unroll
    for (int j = 0; j < 4; j++) acc[i][j] = (f32x4){0.f, 0.f, 0.f, 0.f};

  stage(0, 0);
  VM0();
  BAR();

  const int nt = K >> 6;
  for (int t = 0; t < nt; ++t) {
    const int cur = t & 1;
    bf16x8 a[4][2], b0[2][2], b1[2][2];
    // ---- phase 1: stage next tile, read A-half0 + B-half0, MFMA q(0,0)
    if (t + 1 < nt) stage(cur ^ 1, t + 1);
#pragma unroll
    for (int mi = 0; mi < 4; mi++) {
      a[mi][0] = readA(cur, mi, 0);
      a[mi][1] = readA(cur, mi, 1);
    }
#pragma unroll
    for (int nj = 0; nj < 2; nj++) {
      b0[nj][0] = readB(cur, nj, 0);
      b0[nj][1] = readB(cur, nj, 1);
    }
    BAR();
    LGK0();
    __builtin_amdgcn_s_setprio(1);
#pragma unroll
    for (int mi = 0; mi < 4; mi++)
#pragma unroll
      for (int nj = 0; nj < 2; nj++) {
        acc[mi][nj] = __builtin_amdgcn_mfma_f32_16x16x32_bf16(a[mi][0], b0[nj][0], acc[mi][nj], 0, 0, 0);
        acc[mi][nj] = __builtin_amdgcn_mfma_f32_16x16x32_bf16(a[mi][1], b0[nj][1], acc[mi][nj], 0, 0, 0);
      }
    __builtin_amdgcn_s_setprio(0);
    BAR();
    // ---- phase 2: read B-half1, MFMA q(0,1)
#pragma unroll
    for (int nj = 0; nj < 2; nj++) {
      b1[nj][0] = readB(cur, nj + 2, 0);
      b1[nj][1] = readB(cur, nj + 2, 1);
    }
    BAR();
    LGK0();
    __builtin_amdgcn_s_setprio(1);
#pragma unroll
    for (int mi = 0; mi < 4; mi++)
#pragma unroll
      for (int nj = 0; nj < 2; nj++) {
        acc[mi][nj + 2] = __builtin_amdgcn_mfma_f32_16x16x32_bf16(a[mi][0], b1[nj][0], acc[mi][nj + 2], 0, 0, 0);
        acc[mi][nj + 2] = __builtin_amdgcn_mfma_f32_16x16x32_bf16(a[mi][1], b1[nj][1], acc[mi][nj + 2], 0, 0, 0);
      }
    __builtin_amdgcn_s_setprio(0);
    BAR();
    // ---- phase 3: read A-half1 (reuse regs), MFMA q(1,0)
#pragma unroll
    for (int mi = 0; mi < 4; mi++) {
      a[mi][0] = readA(cur, mi + 4, 0);
      a[mi][1] = readA(cur, mi + 4, 1);
    }
    BAR();
    LGK0();
    __builtin_amdgcn_s_setprio(1);
#pragma unroll
    for (int mi = 0; mi < 4; mi++)
#pragma unroll
      for (int nj = 0; nj < 2; nj++) {
        acc[mi + 4][nj] = __builtin_amdgcn_mfma_f32_16x16x32_bf16(a[mi][0], b0[nj][0], acc[mi + 4][nj], 0, 0, 0);
        acc[mi + 4][nj] = __builtin_amdgcn_mfma_f32_16x16x32_bf16(a[mi][1], b0[nj][1], acc[mi + 4][nj], 0, 0, 0);
      }
    __builtin_amdgcn_s_setprio(0);
    BAR();
    // ---- phase 4: MFMA q(1,1); drain stage loads; tile boundary
    __builtin_amdgcn_s_setprio(1);
#pragma unroll
    for (int mi = 0; mi < 4; mi++)
#pragma unroll
      for (int nj = 0; nj < 2; nj++) {
        acc[mi + 4][nj + 2] = __builtin_amdgcn_mfma_f32_16x16x32_bf16(a[mi][0], b1[nj][0], acc[mi + 4][nj + 2], 0, 0, 0);
        acc[mi + 4][nj + 2] = __builtin_amdgcn_mfma_f32_16x16x32_bf16(a[mi][1], b1[nj][1], acc[mi + 4][nj + 2], 0, 0, 0);
      }
    __builtin_amdgcn_s_setprio(0);
    VM0();
    BAR();
  }

  // ---- epilogue: C row = m0 + wr*128 + mi*16 + (lane>>4)*4 + r, col = n0 + wc*64 + nj*16 + (lane&15)
  const int erow0 = m0 + wr * 128 + (lane >> 4) * 4;
  const int ecol0 = n0 + wc * 64 + (lane & 15);
#pragma unroll
  for (int nj = 0; nj < 4; nj++) {
    const int col = ecol0 + nj * 16;
    const float bv = HAS_BIAS ? bias[col] : 0.0f;
#pragma unroll
    for (int mi = 0; mi < 8; mi++) {
      const int row = erow0 + mi * 16;
      if (OUTMODE == 2) {
        // Vt[b][col][s..s+3], b = row>>11, s = row & 2047 (packed 8B store)
        float v0 = acc[mi][nj][0] * scale + bv;
        float v1 = acc[mi][nj][1] * scale + bv;
        float v2 = acc[mi][nj][2] * scale + bv;
        float v3 = acc[mi][nj][3] * scale + bv;
        unsigned lo = (unsigned)f32_to_bf16(v0) | ((unsigned)f32_to_bf16(v1) << 16);
        unsigned hi = (unsigned)f32_to_bf16(v2) | ((unsigned)f32_to_bf16(v3) << 16);
        size_t off = ((size_t)(row >> 11) * N + col) * (size_t)S + (row & 2047);
        *(uint2*)((unsigned short*)Cv + off) = make_uint2(lo, hi);
      } else {
#pragma unroll
        for (int r = 0; r < 4; r++) {
          float v = acc[mi][nj][r] * scale + bv;
          size_t off = (size_t)bz * bsC + (size_t)(row + r) * N + col;
          if (OUTMODE == 1)
            ((unsigned short*)Cv)[off] = f32_to_bf16(v);
          else
            ((float*)Cv)[off] = v;
        }
      }
    }
  }
}

// ---------------- row softmax over E [B*S][S] bf16, in-place ---------------
__global__ __launch_bounds__(256) void softmax_rows(unsigned short* __restrict__ E,
                                                    const int* __restrict__ mask) {
  const int row = blockIdx.x;  // 0..B*S-1
  const int b = row >> 11, q = row & 2047;
  unsigned short* R = E + (size_t)row * S;
  const int tid = threadIdx.x;
  const int wave = tid >> 6, lane = tid & 63;

  if (mask[b * S + q] == 0) {
    ((uint4*)R)[tid] = make_uint4(0x3A003A00u, 0x3A003A00u, 0x3A003A00u, 0x3A003A00u);
    return;
  }

  uint4 v = ((const uint4*)R)[tid];
  unsigned u[4] = {v.x, v.y, v.z, v.w};
  float f[8];
#pragma unroll
  for (int i = 0; i < 4; i++) {
    f[2 * i] = __uint_as_float(u[i] << 16);
    f[2 * i + 1] = __uint_as_float(u[i] & 0xFFFF0000u);
  }

  __shared__ float red[4];
  float m = f[0];
#pragma unroll
  for (int i = 1; i < 8; i++) m = fmaxf(m, f[i]);
#pragma unroll
  for (int off = 32; off >= 1; off >>= 1) m = fmaxf(m, __shfl_xor(m, off));
  if (lane == 0) red[wave] = m;
  __syncthreads();
  m = fmaxf(fmaxf(red[0], red[1]), fmaxf(red[2], red[3]));
  __syncthreads();

  float s = 0.f;
#pragma unroll
  for (int i = 0; i < 8; i++) {
    f[i] = __expf(f[i] - m);
    s += f[i];
  }
#pragma unroll
  for (int off = 32; off >= 1; off >>= 1) s += __shfl_xor(s, off);
  if (lane == 0) red[wave] = s;
  __syncthreads();
  s = red[0] + red[1] + red[2] + red[3];
  const float inv = 1.0f / s;

  uint4 o;
  unsigned* po = &o.x;
#pragma unroll
  for (int i = 0; i < 4; i++)
    po[i] = (unsigned)f32_to_bf16(f[2 * i] * inv) |
            ((unsigned)f32_to_bf16(f[2 * i + 1] * inv) << 16);
  ((uint4*)R)[tid] = o;
}

// ---------------------------------------------------------------------------
extern "C" void kernel_launch(void* const* d_in, const int* in_sizes, int n_in,
                              void* d_out, int out_size, void* d_ws, size_t ws_size,
                              hipStream_t stream) {
  const float* q = (const float*)d_in[0];
  const float* k_ = (const float*)d_in[1];
  const float* v = (const float*)d_in[2];
  const int* msk = (const int*)d_in[3];
  const float* Wq = (const float*)d_in[4];
  const float* bq = (const float*)d_in[5];
  const float* Wk = (const float*)d_in[6];
  const float* bk = (const float*)d_in[7];
  const float* Wv = (const float*)d_in[8];
  const float* bv = (const float*)d_in[9];
  const float* Wfc = (const float*)d_in[10];
  const float* bfc = (const float*)d_in[11];

  char* ws = (char*)d_ws;
  const size_t MB = 1u << 20;
  unsigned short* WqB = (unsigned short*)(ws + 0 * MB);
  unsigned short* WkB = (unsigned short*)(ws + 2 * MB);
  unsigned short* WvB = (unsigned short*)(ws + 4 * MB);
  unsigned short* WfB = (unsigned short*)(ws + 6 * MB);
  unsigned short* Qb = (unsigned short*)(ws + 8 * MB);    // 32 MB
  unsigned short* Kb = (unsigned short*)(ws + 40 * MB);   // 32 MB
  unsigned short* Vt = (unsigned short*)(ws + 72 * MB);   // 32 MB [b][d][s]
  unsigned short* Ab = (unsigned short*)(ws + 104 * MB);  // 32 MB conv buf / x
  unsigned short* E = (unsigned short*)(ws + 136 * MB);   // 64 MB

  const int NBS = Bb * S * D;

  auto conv = [&](const float* in, unsigned short* out, int n) {
    int n8 = n / 8;
    int blocks = (n8 + 255) / 256;
    if (blocks > 2048) blocks = 2048;
    conv_f32_bf16<<<dim3(blocks), dim3(256), 0, stream>>>(in, out, n8);
  };

  conv(Wq, WqB, D * D);
  conv(Wk, WkB, D * D);
  conv(Wv, WvB, D * D);
  conv(Wfc, WfB, D * D);

  const float invscale = 1.0f / 32.0f;

  // Q = query @ Wq^T + bq
  conv(q, Ab, NBS);
  gemm256<1, true><<<dim3(4, 64, 1), dim3(512), 131072, stream>>>(
      Ab, WqB, bq, Qb, Bb * S, D, D, 0, 0, 0, 1.0f);
  // K = key_ @ Wk^T + bk
  conv(k_, Ab, NBS);
  gemm256<1, true><<<dim3(4, 64, 1), dim3(512), 131072, stream>>>(
      Ab, WkB, bk, Kb, Bb * S, D, D, 0, 0, 0, 1.0f);
  // Vt = (value @ Wv^T + bv)^T per batch (transposed epilogue)
  conv(v, Ab, NBS);
  gemm256<2, true><<<dim3(4, 64, 1), dim3(512), 131072, stream>>>(
      Ab, WvB, bv, Vt, Bb * S, D, D, 0, 0, 0, 1.0f);
  // E = Q @ K^T / 32 (per batch)
  gemm256<1, false><<<dim3(8, 8, 8), dim3(512), 131072, stream>>>(
      Qb, Kb, nullptr, E, S, S, D, (long long)S * D, (long long)S * D,
      (long long)S * S, invscale);
  // P = softmax rows (masked rows -> uniform), in-place
  softmax_rows<<<dim3(Bb * S), dim3(256), 0, stream>>>(E, msk);
  // x = P @ V  (Bt = Vt)
  gemm256<1, false><<<dim3(4, 8, 8), dim3(512), 131072, stream>>>(
      E, Vt, nullptr, Ab, S, D, S, (long long)S * S, (long long)D * S,
      (long long)S * D, 1.0f);
  // out = x @ Wfc^T + bfc (f32 out)
  gemm256<0, true><<<dim3(4, 64, 1), dim3(512), 131072, stream>>>(
      Ab, WfB, bfc, d_out, Bb * S, D, D, 0, 0, 0, 1.0f);
}

// Round 3
// 403.154 us; speedup vs baseline: 1.3026x; 1.0593x over previous
//
#include <hip/hip_runtime.h>
#include <hip/hip_bf16.h>

// SelfAttention: out = (softmax(mask(QK^T/32)) @ V) @ Wfc^T + bfc
// B=8, S=2048, D=1024. bf16 MFMA 16x16x32, 256x256 tile, BK=64, 8 waves,
// m201-style 8-phase schedule (2 K-tiles/iter), counted vmcnt(4), XOR swizzle.

#define DEVINL __device__ __forceinline__

typedef __bf16 bf16x8 __attribute__((ext_vector_type(8)));
typedef float f32x4 __attribute__((ext_vector_type(4)));

static constexpr int Bb = 8;
static constexpr int S = 2048;
static constexpr int D = 1024;

DEVINL unsigned short f32_to_bf16(float f) {
  unsigned u = __float_as_uint(f);
  u = (u + 0x7FFFu + ((u >> 16) & 1u)) >> 16;  // RNE, finite inputs
  return (unsigned short)u;
}

DEVINL void gload16(const unsigned short* g, char* l) {
  __builtin_amdgcn_global_load_lds((__attribute__((address_space(1))) void*)g,
                                   (__attribute__((address_space(3))) void*)l,
                                   16, 0, 0);
}

#define BAR() __builtin_amdgcn_s_barrier()
#define LGK0() asm volatile("s_waitcnt lgkmcnt(0)" ::: "memory")
#define SB0() __builtin_amdgcn_sched_barrier(0)

// open: barrier, drain own ds_reads, pin, boost prio
#define PH_OPEN() \
  BAR();          \
  LGK0();         \
  SB0();          \
  __builtin_amdgcn_s_setprio(1)
#define PH_CLOSE()             \
  __builtin_amdgcn_s_setprio(0); \
  BAR()

#define MFMA_QUAD(A_, B_, MO, NO)                                              \
  {                                                                            \
    _Pragma("unroll") for (int mi_ = 0; mi_ < 4; mi_++) {                      \
      _Pragma("unroll") for (int nj_ = 0; nj_ < 2; nj_++) {                    \
        acc[(MO) + mi_][(NO) + nj_] = __builtin_amdgcn_mfma_f32_16x16x32_bf16( \
            A_[mi_][0], B_[nj_][0], acc[(MO) + mi_][(NO) + nj_], 0, 0, 0);     \
        acc[(MO) + mi_][(NO) + nj_] = __builtin_amdgcn_mfma_f32_16x16x32_bf16( \
            A_[mi_][1], B_[nj_][1], acc[(MO) + mi_][(NO) + nj_], 0, 0, 0);     \
      }                                                                        \
    }                                                                          \
  }

// ---------------- f32 -> bf16 conversion -----------------------------------
__global__ __launch_bounds__(256) void conv_f32_bf16(const float* __restrict__ in,
                                                     unsigned short* __restrict__ out,
                                                     int n8) {
  int i = blockIdx.x * 256 + threadIdx.x;
  int stride = gridDim.x * 256;
  for (; i < n8; i += stride) {
    const float4* p = (const float4*)in + (size_t)i * 2;
    float4 a = p[0], b = p[1];
    uint4 o;
    o.x = (unsigned)f32_to_bf16(a.x) | ((unsigned)f32_to_bf16(a.y) << 16);
    o.y = (unsigned)f32_to_bf16(a.z) | ((unsigned)f32_to_bf16(a.w) << 16);
    o.z = (unsigned)f32_to_bf16(b.x) | ((unsigned)f32_to_bf16(b.y) << 16);
    o.w = (unsigned)f32_to_bf16(b.z) | ((unsigned)f32_to_bf16(b.w) << 16);
    ((uint4*)out)[i] = o;
  }
}

// ---------------- 256x256 GEMM: C[M,N] = A[M,K] * Bt[N,K]^T ----------------
// OUTMODE: 0 = f32, 1 = bf16, 2 = bf16 transposed per-batch (V -> Vt[b][n][s])
// LDS: db in {0,1}: A at db*64K (256 rows x 128B), B at db*64K+32K.
// Physical granule within a row: g_phys = g_log ^ (row & 7).
template <int OUTMODE, bool HAS_BIAS>
__global__ __launch_bounds__(512, 2) void gemm256(
    const unsigned short* __restrict__ A, const unsigned short* __restrict__ Bt,
    const float* __restrict__ bias, void* __restrict__ Cv,
    int M, int N, int K, long long bsA, long long bsB, long long bsC,
    float scale) {
  extern __shared__ char smem[];  // 128 KB
  const int tid = threadIdx.x;
  const int wave = tid >> 6, lane = tid & 63;
  const int wr = wave >> 2, wc = wave & 3;  // 2 x 4 wave grid

  // XCD-aware bijective swizzle (nwg % 8 == 0 for all our launches)
  const int gx = gridDim.x, gy = gridDim.y;
  const int nwg = gx * gy * (int)gridDim.z;
  const int wg = blockIdx.x + gx * (blockIdx.y + gy * blockIdx.z);
  const int swz = (wg & 7) * (nwg >> 3) + (wg >> 3);
  const int bx = swz % gx;
  const int rem = swz / gx;
  const int by = rem % gy;
  const int bz = rem / gy;

  const int m0 = by * 256, n0 = bx * 256;
  A += (size_t)bz * bsA;
  Bt += (size_t)bz * bsB;

  // ---- staging: one half-tile (128 rows x 64 k of A or B) per call.
  // 512 threads x 2 gload16: load i covers rows i*64 + wave*8 + (lane>>3),
  // phys granule lane&7  ->  fetch logical granule (lane&7)^(lane>>3).
  const int rl = lane >> 3;
  const int gl = (lane & 7) ^ rl;
  const unsigned short* gA = A + (size_t)(m0 + wave * 8 + rl) * K + gl * 8;
  const unsigned short* gB = Bt + (size_t)(n0 + wave * 8 + rl) * K + gl * 8;

  auto stageA = [&](int db, int t, int h) {
    const unsigned short* g = gA + (size_t)(h * 128) * K + (size_t)t * 64;
    char* l = smem + db * 65536 + h * 16384 + wave * 1024;
    gload16(g, l);
    gload16(g + (size_t)64 * K, l + 8192);
  };
  auto stageB = [&](int db, int t, int h) {
    const unsigned short* g = gB + (size_t)(h * 128) * K + (size_t)t * 64;
    char* l = smem + db * 65536 + 32768 + h * 16384 + wave * 1024;
    gload16(g, l);
    gload16(g + (size_t)64 * K, l + 8192);
  };

  const int fr = lane & 15;  // row within 16x16 frag
  const int fg = lane >> 4;  // k-granule sub-index (0..3)
  auto readA = [&](int db, int mi, int kc) -> bf16x8 {
    const int row = wr * 128 + mi * 16 + fr;
    const int g = (kc * 4 + fg) ^ (row & 7);
    return *(const bf16x8*)(smem + db * 65536 + row * 128 + g * 16);
  };
  auto readB = [&](int db, int nj, int kc) -> bf16x8 {
    const int row = wc * 64 + nj * 16 + fr;
    const int g = (kc * 4 + fg) ^ (row & 7);
    return *(const bf16x8*)(smem + db * 65536 + 32768 + row * 128 + g * 16);
  };

  f32x4 acc[8][4];
#pragma unroll
  for (int i = 0; i < 8; i++)
#pragma unroll
    for (int j = 0; j < 4; j++) acc[i][j] = (f32x4){0.f, 0.f, 0.f, 0.f};

  // ---- prologue: tile 0 fully + B halves of tile 1; allow B(t1) in flight
  stageA(0, 0, 0);
  stageA(0, 0, 1);
  stageB(0, 0, 0);
  stageB(0, 0, 1);
  stageB(1, 1, 0);
  stageB(1, 1, 1);
  asm volatile("s_waitcnt vmcnt(4)" ::: "memory");
  BAR();

  const int nt = K >> 6;       // even (K = 1024 or 2048)
  const int niter = nt >> 1;   // 2 K-tiles per iteration

  for (int j = 0; j < niter; ++j) {
    const int t0 = 2 * j, t1 = 2 * j + 1;
    const bool more = (j + 1 < niter);
    bf16x8 a[4][2], b0[2][2], b1[2][2];

    // ---- P1: read A0+B0 (db0); stage A0(t1)->db1; MFMA q(0,0)
#pragma unroll
    for (int mi = 0; mi < 4; mi++) {
      a[mi][0] = readA(0, mi, 0);
      a[mi][1] = readA(0, mi, 1);
    }
#pragma unroll
    for (int nj = 0; nj < 2; nj++) {
      b0[nj][0] = readB(0, nj, 0);
      b0[nj][1] = readB(0, nj, 1);
    }
    stageA(1, t1, 0);
    asm volatile("s_waitcnt lgkmcnt(8)" ::: "memory");
    PH_OPEN();
    MFMA_QUAD(a, b0, 0, 0);
    PH_CLOSE();

    // ---- P2: read B1 (db0); stage A1(t1)->db1; MFMA q(0,1)
#pragma unroll
    for (int nj = 0; nj < 2; nj++) {
      b1[nj][0] = readB(0, nj + 2, 0);
      b1[nj][1] = readB(0, nj + 2, 1);
    }
    stageA(1, t1, 1);
    PH_OPEN();
    MFMA_QUAD(a, b1, 0, 2);
    PH_CLOSE();

    // ---- P3: read A1 (db0); stage B0(t0+2)->db0; MFMA q(1,0)
#pragma unroll
    for (int mi = 0; mi < 4; mi++) {
      a[mi][0] = readA(0, mi + 4, 0);
      a[mi][1] = readA(0, mi + 4, 1);
    }
    if (more) stageB(0, t0 + 2, 0);
    PH_OPEN();
    MFMA_QUAD(a, b0, 4, 0);
    PH_CLOSE();

    // ---- P4: stage B1(t0+2)->db0; MFMA q(1,1); counted wait for A/B(t1)
    if (more) stageB(0, t0 + 2, 1);
    BAR();
    __builtin_amdgcn_s_setprio(1);
    MFMA_QUAD(a, b1, 4, 2);
    __builtin_amdgcn_s_setprio(0);
    if (more)
      asm volatile("s_waitcnt vmcnt(4)" ::: "memory");
    else
      asm volatile("s_waitcnt vmcnt(0)" ::: "memory");
    BAR();

    // ---- P5: read A0+B0 (db1, tile t1); stage A0(t0+2)->db0; MFMA q(0,0)
#pragma unroll
    for (int mi = 0; mi < 4; mi++) {
      a[mi][0] = readA(1, mi, 0);
      a[mi][1] = readA(1, mi, 1);
    }
#pragma unroll
    for (int nj = 0; nj < 2; nj++) {
      b0[nj][0] = readB(1, nj, 0);
      b0[nj][1] = readB(1, nj, 1);
    }
    if (more) stageA(0, t0 + 2, 0);
    asm volatile("s_waitcnt lgkmcnt(8)" ::: "memory");
    PH_OPEN();
    MFMA_QUAD(a, b0, 0, 0);
    PH_CLOSE();

    // ---- P6: read B1 (db1); stage A1(t0+2)->db0; MFMA q(0,1)
#pragma unroll
    for (int nj = 0; nj < 2; nj++) {
      b1[nj][0] = readB(1, nj + 2, 0);
      b1[nj][1] = readB(1, nj + 2, 1);
    }
    if (more) stageA(0, t0 + 2, 1);
    PH_OPEN();
    MFMA_QUAD(a, b1, 0, 2);
    PH_CLOSE();

    // ---- P7: read A1 (db1); stage B0(t1+2)->db1; MFMA q(1,0)
#pragma unroll
    for (int mi = 0; mi < 4; mi++) {
      a[mi][0] = readA(1, mi + 4, 0);
      a[mi][1] = readA(1, mi + 4, 1);
    }
    if (more) stageB(1, t1 + 2, 0);
    PH_OPEN();
    MFMA_QUAD(a, b0, 4, 0);
    PH_CLOSE();

    // ---- P8: stage B1(t1+2)->db1; MFMA q(1,1); counted wait for tile t0+2
    if (more) stageB(1, t1 + 2, 1);
    BAR();
    __builtin_amdgcn_s_setprio(1);
    MFMA_QUAD(a, b1, 4, 2);
    __builtin_amdgcn_s_setprio(0);
    asm volatile("s_waitcnt vmcnt(4)" ::: "memory");
    BAR();
  }

  // ---- epilogue
  const int erow0 = m0 + wr * 128 + (lane >> 4) * 4;
  const int ecol0 = n0 + wc * 64 + (lane & 15);
#pragma unroll
  for (int nj = 0; nj < 4; nj++) {
    const int col = ecol0 + nj * 16;
    const float bv = HAS_BIAS ? bias[col] : 0.0f;
#pragma unroll
    for (int mi = 0; mi < 8; mi++) {
      const int row = erow0 + mi * 16;
      if (OUTMODE == 2) {
        float v0 = acc[mi][nj][0] * scale + bv;
        float v1 = acc[mi][nj][1] * scale + bv;
        float v2 = acc[mi][nj][2] * scale + bv;
        float v3 = acc[mi][nj][3] * scale + bv;
        unsigned lo = (unsigned)f32_to_bf16(v0) | ((unsigned)f32_to_bf16(v1) << 16);
        unsigned hi = (unsigned)f32_to_bf16(v2) | ((unsigned)f32_to_bf16(v3) << 16);
        size_t off = ((size_t)(row >> 11) * N + col) * (size_t)S + (row & 2047);
        *(uint2*)((unsigned short*)Cv + off) = make_uint2(lo, hi);
      } else {
#pragma unroll
        for (int r = 0; r < 4; r++) {
          float v = acc[mi][nj][r] * scale + bv;
          size_t off = (size_t)bz * bsC + (size_t)(row + r) * N + col;
          if (OUTMODE == 1)
            ((unsigned short*)Cv)[off] = f32_to_bf16(v);
          else
            ((float*)Cv)[off] = v;
        }
      }
    }
  }
}

// ---------------- row softmax over E [B*S][S] bf16, in-place ---------------
__global__ __launch_bounds__(256) void softmax_rows(unsigned short* __restrict__ E,
                                                    const int* __restrict__ mask) {
  const int row = blockIdx.x;  // 0..B*S-1
  const int b = row >> 11, q = row & 2047;
  unsigned short* R = E + (size_t)row * S;
  const int tid = threadIdx.x;
  const int wave = tid >> 6, lane = tid & 63;

  if (mask[b * S + q] == 0) {
    ((uint4*)R)[tid] = make_uint4(0x3A003A00u, 0x3A003A00u, 0x3A003A00u, 0x3A003A00u);
    return;
  }

  uint4 v = ((const uint4*)R)[tid];
  unsigned u[4] = {v.x, v.y, v.z, v.w};
  float f[8];
#pragma unroll
  for (int i = 0; i < 4; i++) {
    f[2 * i] = __uint_as_float(u[i] << 16);
    f[2 * i + 1] = __uint_as_float(u[i] & 0xFFFF0000u);
  }

  __shared__ float red[4];
  float m = f[0];
#pragma unroll
  for (int i = 1; i < 8; i++) m = fmaxf(m, f[i]);
#pragma unroll
  for (int off = 32; off >= 1; off >>= 1) m = fmaxf(m, __shfl_xor(m, off));
  if (lane == 0) red[wave] = m;
  __syncthreads();
  m = fmaxf(fmaxf(red[0], red[1]), fmaxf(red[2], red[3]));
  __syncthreads();

  float s = 0.f;
#pragma unroll
  for (int i = 0; i < 8; i++) {
    f[i] = __expf(f[i] - m);
    s += f[i];
  }
#pragma unroll
  for (int off = 32; off >= 1; off >>= 1) s += __shfl_xor(s, off);
  if (lane == 0) red[wave] = s;
  __syncthreads();
  s = red[0] + red[1] + red[2] + red[3];
  const float inv = 1.0f / s;

  uint4 o;
  unsigned* po = &o.x;
#pragma unroll
  for (int i = 0; i < 4; i++)
    po[i] = (unsigned)f32_to_bf16(f[2 * i] * inv) |
            ((unsigned)f32_to_bf16(f[2 * i + 1] * inv) << 16);
  ((uint4*)R)[tid] = o;
}

// ---------------------------------------------------------------------------
extern "C" void kernel_launch(void* const* d_in, const int* in_sizes, int n_in,
                              void* d_out, int out_size, void* d_ws, size_t ws_size,
                              hipStream_t stream) {
  const float* q = (const float*)d_in[0];
  const float* k_ = (const float*)d_in[1];
  const float* v = (const float*)d_in[2];
  const int* msk = (const int*)d_in[3];
  const float* Wq = (const float*)d_in[4];
  const float* bq = (const float*)d_in[5];
  const float* Wk = (const float*)d_in[6];
  const float* bk = (const float*)d_in[7];
  const float* Wv = (const float*)d_in[8];
  const float* bv = (const float*)d_in[9];
  const float* Wfc = (const float*)d_in[10];
  const float* bfc = (const float*)d_in[11];

  char* ws = (char*)d_ws;
  const size_t MB = 1u << 20;
  unsigned short* WqB = (unsigned short*)(ws + 0 * MB);
  unsigned short* WkB = (unsigned short*)(ws + 2 * MB);
  unsigned short* WvB = (unsigned short*)(ws + 4 * MB);
  unsigned short* WfB = (unsigned short*)(ws + 6 * MB);
  unsigned short* Qb = (unsigned short*)(ws + 8 * MB);    // 32 MB
  unsigned short* Kb = (unsigned short*)(ws + 40 * MB);   // 32 MB
  unsigned short* Vt = (unsigned short*)(ws + 72 * MB);   // 32 MB [b][d][s]
  unsigned short* Ab = (unsigned short*)(ws + 104 * MB);  // 32 MB conv buf / x
  unsigned short* E = (unsigned short*)(ws + 136 * MB);   // 64 MB

  const int NBS = Bb * S * D;

  auto conv = [&](const float* in, unsigned short* out, int n) {
    int n8 = n / 8;
    int blocks = (n8 + 255) / 256;
    if (blocks > 2048) blocks = 2048;
    conv_f32_bf16<<<dim3(blocks), dim3(256), 0, stream>>>(in, out, n8);
  };

  conv(Wq, WqB, D * D);
  conv(Wk, WkB, D * D);
  conv(Wv, WvB, D * D);
  conv(Wfc, WfB, D * D);

  const float invscale = 1.0f / 32.0f;

  // Q = query @ Wq^T + bq
  conv(q, Ab, NBS);
  gemm256<1, true><<<dim3(4, 64, 1), dim3(512), 131072, stream>>>(
      Ab, WqB, bq, Qb, Bb * S, D, D, 0, 0, 0, 1.0f);
  // K = key_ @ Wk^T + bk
  conv(k_, Ab, NBS);
  gemm256<1, true><<<dim3(4, 64, 1), dim3(512), 131072, stream>>>(
      Ab, WkB, bk, Kb, Bb * S, D, D, 0, 0, 0, 1.0f);
  // Vt = (value @ Wv^T + bv)^T per batch (transposed epilogue)
  conv(v, Ab, NBS);
  gemm256<2, true><<<dim3(4, 64, 1), dim3(512), 131072, stream>>>(
      Ab, WvB, bv, Vt, Bb * S, D, D, 0, 0, 0, 1.0f);
  // E = Q @ K^T / 32 (per batch)
  gemm256<1, false><<<dim3(8, 8, 8), dim3(512), 131072, stream>>>(
      Qb, Kb, nullptr, E, S, S, D, (long long)S * D, (long long)S * D,
      (long long)S * S, invscale);
  // P = softmax rows (masked rows -> uniform), in-place
  softmax_rows<<<dim3(Bb * S), dim3(256), 0, stream>>>(E, msk);
  // x = P @ V  (Bt = Vt)
  gemm256<1, false><<<dim3(4, 8, 8), dim3(512), 131072, stream>>>(
      E, Vt, nullptr, Ab, S, D, S, (long long)S * S, (long long)D * S,
      (long long)S * D, 1.0f);
  // out = x @ Wfc^T + bfc (f32 out)
  gemm256<0, true><<<dim3(4, 64, 1), dim3(512), 131072, stream>>>(
      Ab, WfB, bfc, d_out, Bb * S, D, D, 0, 0, 0, 1.0f);
}